// Round 1
// baseline (171.907 us; speedup 1.0000x reference)
//
#include <hip/hip_runtime.h>

// LaplacianRegLoss: res[b,n,d] = (lapdiff[b,n,d])^2 where
//   lapdiff = diff + sum_k w[n,k] * diff[b, idx[n,k], d],  diff = out - target
// B=16, N=100000, K=10, D=3. All fp32; idx int32.

#define BB 16
#define NN 100000
#define KK 10
#define DD 3

__global__ __launch_bounds__(256) void LaplacianRegLoss_kernel(
    const float* __restrict__ out,
    const float* __restrict__ tgt,
    const int* __restrict__ nidx,
    const float* __restrict__ nw,
    float* __restrict__ res) {
    int n = blockIdx.x * blockDim.x + threadIdx.x;
    if (n >= NN) return;
    int b = blockIdx.y;

    // Load this row's neighbor indices and weights (shared across b, L3-cached).
    int idxs[KK];
    float wts[KK];
#pragma unroll
    for (int k = 0; k < KK; ++k) {
        idxs[k] = nidx[n * KK + k];
        wts[k] = nw[n * KK + k];
    }

    const float* ob = out + (size_t)b * (NN * DD);
    const float* tb = tgt + (size_t)b * (NN * DD);

    int base = n * DD;
    float s0 = ob[base + 0] - tb[base + 0];
    float s1 = ob[base + 1] - tb[base + 1];
    float s2 = ob[base + 2] - tb[base + 2];

#pragma unroll
    for (int k = 0; k < KK; ++k) {
        int j = idxs[k] * DD;
        float w = wts[k];
        s0 += w * (ob[j + 0] - tb[j + 0]);
        s1 += w * (ob[j + 1] - tb[j + 1]);
        s2 += w * (ob[j + 2] - tb[j + 2]);
    }

    float* rb = res + (size_t)b * (NN * DD);
    rb[base + 0] = s0 * s0;
    rb[base + 1] = s1 * s1;
    rb[base + 2] = s2 * s2;
}

extern "C" void kernel_launch(void* const* d_in, const int* in_sizes, int n_in,
                              void* d_out, int out_size, void* d_ws, size_t ws_size,
                              hipStream_t stream) {
    const float* out = (const float*)d_in[0];
    const float* tgt = (const float*)d_in[1];
    const int* nidx = (const int*)d_in[2];
    const float* nw = (const float*)d_in[3];
    float* res = (float*)d_out;

    dim3 block(256);
    dim3 grid((NN + 255) / 256, BB);
    LaplacianRegLoss_kernel<<<grid, block, 0, stream>>>(out, tgt, nidx, nw, res);
}

// Round 2
// 73.309 us; speedup vs baseline: 2.3450x; 2.3450x over previous
//
#include <hip/hip_runtime.h>

// LaplacianRegLoss: res[b,n,d] = (lap(diff)[b,n,d])^2, diff = out - target,
// lap(x)[b,n,d] = x[b,n,d] + sum_k w[n,k] * x[b, idx[n,k], d]
// B=16, N=100000, K=10, D=3. All fp32; idx int32.
//
// Two-pass scheme:
//  pass1: tdiff[n][d][b] = out[b][n][d] - tgt[b][n][d]   (transposed diff, b inner)
//  pass2: per node n, gather tdiff[idx][.][.] (192B contiguous, all batches share),
//         accumulate, square, write res[b][n][d].

#define BB 16
#define NN 100000
#define KK 10
#define DD 3
// tdiff row: DD*BB = 48 floats = 192 bytes per node
#define TROW 48

__global__ __launch_bounds__(256) void lap_pass1(
    const float* __restrict__ o,
    const float* __restrict__ t,
    float* __restrict__ td) {
    int tid = threadIdx.x;
    int b = tid >> 4;        // 0..15
    int nl = tid & 15;       // 16 consecutive nodes per b-group -> coalesced reads
    int n = blockIdx.x * 16 + nl;
    size_t ro = (size_t)b * (NN * DD) + (size_t)n * DD;
    float d0 = o[ro + 0] - t[ro + 0];
    float d1 = o[ro + 1] - t[ro + 1];
    float d2 = o[ro + 2] - t[ro + 2];
    size_t wo = (size_t)n * TROW + b;   // [n][d][b]
    td[wo + 0]  = d0;
    td[wo + 16] = d1;
    td[wo + 32] = d2;
}

#define FMA4(s, q) { s.x += w * q.x; s.y += w * q.y; s.z += w * q.z; s.w += w * q.w; }

__global__ __launch_bounds__(256) void lap_pass2(
    const float* __restrict__ td,
    const int* __restrict__ nidx,
    const float* __restrict__ nw,
    float* __restrict__ res) {
    int nl = threadIdx.x & 63;      // 64 consecutive nodes per wave
    int g = threadIdx.x >> 6;       // batch group 0..3 (wave-uniform)
    int n = blockIdx.x * 64 + nl;
    if (n >= NN) return;

    const float4* t4 = (const float4*)td;  // 12 float4 per node row

    int idxs[KK];
    float wts[KK];
#pragma unroll
    for (int k = 0; k < KK; ++k) {
        idxs[k] = nidx[n * KK + k];
        wts[k] = nw[n * KK + k];
    }

    int base = n * 12 + g;          // float4 index: n*12 + d*4 + g
    float4 s0 = t4[base + 0];       // d=0, batches 4g..4g+3
    float4 s1 = t4[base + 4];       // d=1
    float4 s2 = t4[base + 8];       // d=2

#pragma unroll
    for (int k = 0; k < KK; ++k) {
        int j = idxs[k] * 12 + g;
        float w = wts[k];
        float4 q0 = t4[j + 0];
        float4 q1 = t4[j + 4];
        float4 q2 = t4[j + 8];
        FMA4(s0, q0);
        FMA4(s1, q1);
        FMA4(s2, q2);
    }

    int g4 = g * 4;
    {
        size_t o = (size_t)(g4 + 0) * (NN * DD) + (size_t)n * DD;
        res[o + 0] = s0.x * s0.x; res[o + 1] = s1.x * s1.x; res[o + 2] = s2.x * s2.x;
    }
    {
        size_t o = (size_t)(g4 + 1) * (NN * DD) + (size_t)n * DD;
        res[o + 0] = s0.y * s0.y; res[o + 1] = s1.y * s1.y; res[o + 2] = s2.y * s2.y;
    }
    {
        size_t o = (size_t)(g4 + 2) * (NN * DD) + (size_t)n * DD;
        res[o + 0] = s0.z * s0.z; res[o + 1] = s1.z * s1.z; res[o + 2] = s2.z * s2.z;
    }
    {
        size_t o = (size_t)(g4 + 3) * (NN * DD) + (size_t)n * DD;
        res[o + 0] = s0.w * s0.w; res[o + 1] = s1.w * s1.w; res[o + 2] = s2.w * s2.w;
    }
}

// Fallback single-pass kernel (used only if ws_size is too small).
__global__ __launch_bounds__(256) void lap_naive(
    const float* __restrict__ out,
    const float* __restrict__ tgt,
    const int* __restrict__ nidx,
    const float* __restrict__ nw,
    float* __restrict__ res) {
    int n = blockIdx.x * blockDim.x + threadIdx.x;
    if (n >= NN) return;
    int b = blockIdx.y;
    int idxs[KK];
    float wts[KK];
#pragma unroll
    for (int k = 0; k < KK; ++k) {
        idxs[k] = nidx[n * KK + k];
        wts[k] = nw[n * KK + k];
    }
    const float* ob = out + (size_t)b * (NN * DD);
    const float* tb = tgt + (size_t)b * (NN * DD);
    int base = n * DD;
    float s0 = ob[base + 0] - tb[base + 0];
    float s1 = ob[base + 1] - tb[base + 1];
    float s2 = ob[base + 2] - tb[base + 2];
#pragma unroll
    for (int k = 0; k < KK; ++k) {
        int j = idxs[k] * DD;
        float w = wts[k];
        s0 += w * (ob[j + 0] - tb[j + 0]);
        s1 += w * (ob[j + 1] - tb[j + 1]);
        s2 += w * (ob[j + 2] - tb[j + 2]);
    }
    float* rb = res + (size_t)b * (NN * DD);
    rb[base + 0] = s0 * s0;
    rb[base + 1] = s1 * s1;
    rb[base + 2] = s2 * s2;
}

extern "C" void kernel_launch(void* const* d_in, const int* in_sizes, int n_in,
                              void* d_out, int out_size, void* d_ws, size_t ws_size,
                              hipStream_t stream) {
    const float* out = (const float*)d_in[0];
    const float* tgt = (const float*)d_in[1];
    const int* nidx = (const int*)d_in[2];
    const float* nw = (const float*)d_in[3];
    float* res = (float*)d_out;

    const size_t need = (size_t)NN * TROW * sizeof(float);  // 19.2 MB
    if (ws_size >= need) {
        float* td = (float*)d_ws;
        lap_pass1<<<NN / 16, 256, 0, stream>>>(out, tgt, td);
        lap_pass2<<<(NN + 63) / 64, 256, 0, stream>>>(td, nidx, nw, res);
    } else {
        dim3 grid((NN + 255) / 256, BB);
        lap_naive<<<grid, dim3(256), 0, stream>>>(out, tgt, nidx, nw, res);
    }
}

// Round 3
// 59.147 us; speedup vs baseline: 2.9064x; 1.2394x over previous
//
#include <hip/hip_runtime.h>

// LaplacianRegLoss: res[b,n,d] = (lap(diff)[b,n,d])^2, diff = out - target,
// lap(x)[b,n,d] = x[b,n,d] + sum_k w[n,k] * x[b, idx[n,k], d]
// B=16, N=100000, K=10, D=3. All fp32; idx int32.
//
// Two-pass scheme:
//  pass1: tdiff[n][d][b] = out[b][n][d] - tgt[b][n][d]   (transposed diff, b inner)
//  pass2: 4 adjacent lanes per node (g = lane&3); each gather row (192B) is read
//         as 3 coalesced 64B segments by the 4-lane group.

#define BB 16
#define NN 100000
#define KK 10
#define DD 3
// tdiff row: DD*BB = 48 floats = 192 bytes per node
#define TROW 48

__global__ __launch_bounds__(256) void lap_pass1(
    const float* __restrict__ o,
    const float* __restrict__ t,
    float* __restrict__ td) {
    int tid = threadIdx.x;
    int b = tid >> 4;        // 0..15
    int nl = tid & 15;       // 16 consecutive nodes per b-group -> coalesced reads
    int n = blockIdx.x * 16 + nl;
    size_t ro = (size_t)b * (NN * DD) + (size_t)n * DD;
    float d0 = o[ro + 0] - t[ro + 0];
    float d1 = o[ro + 1] - t[ro + 1];
    float d2 = o[ro + 2] - t[ro + 2];
    size_t wo = (size_t)n * TROW + b;   // [n][d][b]
    td[wo + 0]  = d0;
    td[wo + 16] = d1;
    td[wo + 32] = d2;
}

#define FMA4(s, q) { s.x += w * q.x; s.y += w * q.y; s.z += w * q.z; s.w += w * q.w; }

__global__ __launch_bounds__(256) void lap_pass2(
    const float* __restrict__ td,
    const int* __restrict__ nidx,
    const float* __restrict__ nw,
    float* __restrict__ res) {
    int tid = threadIdx.x;
    int n = blockIdx.x * 64 + (tid >> 2);   // 64 nodes per block
    int g = tid & 3;                         // batch group on ADJACENT lanes
    if (n >= NN) return;

    const float4* t4 = (const float4*)td;  // 12 float4 per node row

    int idxs[KK];
    float wts[KK];
#pragma unroll
    for (int k = 0; k < KK; ++k) {
        idxs[k] = nidx[n * KK + k];
        wts[k] = nw[n * KK + k];
    }

    int base = n * 12 + g;          // float4 index: n*12 + d*4 + g
    float4 s0 = t4[base + 0];       // d=0, batches 4g..4g+3
    float4 s1 = t4[base + 4];       // d=1
    float4 s2 = t4[base + 8];       // d=2

#pragma unroll
    for (int k = 0; k < KK; ++k) {
        int j = idxs[k] * 12 + g;
        float w = wts[k];
        float4 q0 = t4[j + 0];      // 4 lanes (g=0..3) -> one 64B segment
        float4 q1 = t4[j + 4];
        float4 q2 = t4[j + 8];
        FMA4(s0, q0);
        FMA4(s1, q1);
        FMA4(s2, q2);
    }

    int g4 = g * 4;
    {
        size_t o = (size_t)(g4 + 0) * (NN * DD) + (size_t)n * DD;
        res[o + 0] = s0.x * s0.x; res[o + 1] = s1.x * s1.x; res[o + 2] = s2.x * s2.x;
    }
    {
        size_t o = (size_t)(g4 + 1) * (NN * DD) + (size_t)n * DD;
        res[o + 0] = s0.y * s0.y; res[o + 1] = s1.y * s1.y; res[o + 2] = s2.y * s2.y;
    }
    {
        size_t o = (size_t)(g4 + 2) * (NN * DD) + (size_t)n * DD;
        res[o + 0] = s0.z * s0.z; res[o + 1] = s1.z * s1.z; res[o + 2] = s2.z * s2.z;
    }
    {
        size_t o = (size_t)(g4 + 3) * (NN * DD) + (size_t)n * DD;
        res[o + 0] = s0.w * s0.w; res[o + 1] = s1.w * s1.w; res[o + 2] = s2.w * s2.w;
    }
}

// Fallback single-pass kernel (used only if ws_size is too small).
__global__ __launch_bounds__(256) void lap_naive(
    const float* __restrict__ out,
    const float* __restrict__ tgt,
    const int* __restrict__ nidx,
    const float* __restrict__ nw,
    float* __restrict__ res) {
    int n = blockIdx.x * blockDim.x + threadIdx.x;
    if (n >= NN) return;
    int b = blockIdx.y;
    int idxs[KK];
    float wts[KK];
#pragma unroll
    for (int k = 0; k < KK; ++k) {
        idxs[k] = nidx[n * KK + k];
        wts[k] = nw[n * KK + k];
    }
    const float* ob = out + (size_t)b * (NN * DD);
    const float* tb = tgt + (size_t)b * (NN * DD);
    int base = n * DD;
    float s0 = ob[base + 0] - tb[base + 0];
    float s1 = ob[base + 1] - tb[base + 1];
    float s2 = ob[base + 2] - tb[base + 2];
#pragma unroll
    for (int k = 0; k < KK; ++k) {
        int j = idxs[k] * DD;
        float w = wts[k];
        s0 += w * (ob[j + 0] - tb[j + 0]);
        s1 += w * (ob[j + 1] - tb[j + 1]);
        s2 += w * (ob[j + 2] - tb[j + 2]);
    }
    float* rb = res + (size_t)b * (NN * DD);
    rb[base + 0] = s0 * s0;
    rb[base + 1] = s1 * s1;
    rb[base + 2] = s2 * s2;
}

extern "C" void kernel_launch(void* const* d_in, const int* in_sizes, int n_in,
                              void* d_out, int out_size, void* d_ws, size_t ws_size,
                              hipStream_t stream) {
    const float* out = (const float*)d_in[0];
    const float* tgt = (const float*)d_in[1];
    const int* nidx = (const int*)d_in[2];
    const float* nw = (const float*)d_in[3];
    float* res = (float*)d_out;

    const size_t need = (size_t)NN * TROW * sizeof(float);  // 19.2 MB
    if (ws_size >= need) {
        float* td = (float*)d_ws;
        lap_pass1<<<NN / 16, 256, 0, stream>>>(out, tgt, td);
        lap_pass2<<<(NN + 63) / 64, 256, 0, stream>>>(td, nidx, nw, res);
    } else {
        dim3 grid((NN + 255) / 256, BB);
        lap_naive<<<grid, dim3(256), 0, stream>>>(out, tgt, nidx, nw, res);
    }
}

// Round 4
// 40.917 us; speedup vs baseline: 4.2014x; 1.4455x over previous
//
#include <hip/hip_runtime.h>

// LaplacianRegLoss: res[b,n,d] = (lap(diff)[b,n,d])^2, diff = out - target,
// lap(x)[b,n,d] = x[b,n,d] + sum_k w[n,k] * x[b, idx[n,k], d]
// B=16, N=100000, K=10, D=3. Inputs fp32; idx int32; output fp32.
//
// Two-pass scheme with fp16 transposed diff:
//  pass1: tdiff[n][d][b] = (half)(out[b][n][d] - tgt[b][n][d])  via LDS transpose,
//         fully coalesced read AND write. Row = 48 halves = 96 B per node.
//  pass2: 2 adjacent lanes per node (g = lane&1); each lane owns 8 batches.
//         Gather row read as 3 d-slices of 32 B contiguous per lane pair.

#define BB 16
#define NN 100000
#define KK 10
#define DD 3
#define TROW 48          // halves per node row (D*B)
#define NB1 160          // nodes per pass1 block (100000 = 625*160, exact)
#define NB2 160          // nodes per pass2 block (320 threads)

typedef _Float16 half8 __attribute__((ext_vector_type(8)));

__global__ __launch_bounds__(256) void lap_pass1(
    const float* __restrict__ o,
    const float* __restrict__ t,
    _Float16* __restrict__ td) {
    __shared__ _Float16 tile[NB1 * TROW];   // 15360 B
    int tid = threadIdx.x;
    size_t base = (size_t)blockIdx.x * (NB1 * DD);

    // i takes two fixed values per thread: tid and tid+256 (NB1*DD = 480)
#pragma unroll
    for (int ii = 0; ii < 2; ++ii) {
        int i = tid + ii * 256;
        if (i < NB1 * DD) {
            int nl = i / 3;
            int dd = i - nl * 3;
            int lo = nl * TROW + dd * 16;   // LDS half-offset, +b below
            for (int b = 0; b < BB; ++b) {
                size_t rb = (size_t)b * (NN * DD) + base + i;
                tile[lo + b] = (_Float16)(o[rb] - t[rb]);
            }
        }
    }
    __syncthreads();

    // coalesced write: NB1*TROW halves = 15360 B = 960 uint4
    const uint4* src = (const uint4*)tile;
    uint4* dst = (uint4*)(td + (size_t)blockIdx.x * (NB1 * TROW));
#pragma unroll
    for (int ii = 0; ii < 4; ++ii) {
        int i = tid + ii * 256;
        if (i < NB1 * TROW / 8) dst[i] = src[i];
    }
}

__global__ __launch_bounds__(320) void lap_pass2(
    const _Float16* __restrict__ td,
    const int* __restrict__ nidx,
    const float* __restrict__ nw,
    float* __restrict__ res) {
    int tid = threadIdx.x;
    int n = blockIdx.x * NB2 + (tid >> 1);
    int g = tid & 1;                       // batch half on ADJACENT lanes

    const half8* t8 = (const half8*)td;    // 6 half8 per node row

    int idxs[KK];
    float wts[KK];
#pragma unroll
    for (int k = 0; k < KK; ++k) {
        idxs[k] = nidx[n * KK + k];
        wts[k] = nw[n * KK + k];
    }

    float s[DD][8];
    int base = n * 6 + g;                  // half8 index; d stride = 2
#pragma unroll
    for (int d = 0; d < DD; ++d) {
        half8 q = t8[base + d * 2];
#pragma unroll
        for (int i = 0; i < 8; ++i) s[d][i] = (float)q[i];
    }

#pragma unroll
    for (int k = 0; k < KK; ++k) {
        int j = idxs[k] * 6 + g;
        float w = wts[k];
#pragma unroll
        for (int d = 0; d < DD; ++d) {
            half8 q = t8[j + d * 2];       // lane pair covers 32B contiguous
#pragma unroll
            for (int i = 0; i < 8; ++i) s[d][i] += w * (float)q[i];
        }
    }

#pragma unroll
    for (int i = 0; i < 8; ++i) {
        int b = g * 8 + i;
        size_t o = (size_t)b * (NN * DD) + (size_t)n * DD;
#pragma unroll
        for (int d = 0; d < DD; ++d) res[o + d] = s[d][i] * s[d][i];
    }
}

// Fallback single-pass kernel (used only if ws_size is too small).
__global__ __launch_bounds__(256) void lap_naive(
    const float* __restrict__ out,
    const float* __restrict__ tgt,
    const int* __restrict__ nidx,
    const float* __restrict__ nw,
    float* __restrict__ res) {
    int n = blockIdx.x * blockDim.x + threadIdx.x;
    if (n >= NN) return;
    int b = blockIdx.y;
    int idxs[KK];
    float wts[KK];
#pragma unroll
    for (int k = 0; k < KK; ++k) {
        idxs[k] = nidx[n * KK + k];
        wts[k] = nw[n * KK + k];
    }
    const float* ob = out + (size_t)b * (NN * DD);
    const float* tb = tgt + (size_t)b * (NN * DD);
    int base = n * DD;
    float s0 = ob[base + 0] - tb[base + 0];
    float s1 = ob[base + 1] - tb[base + 1];
    float s2 = ob[base + 2] - tb[base + 2];
#pragma unroll
    for (int k = 0; k < KK; ++k) {
        int j = idxs[k] * DD;
        float w = wts[k];
        s0 += w * (ob[j + 0] - tb[j + 0]);
        s1 += w * (ob[j + 1] - tb[j + 1]);
        s2 += w * (ob[j + 2] - tb[j + 2]);
    }
    float* rb = res + (size_t)b * (NN * DD);
    rb[base + 0] = s0 * s0;
    rb[base + 1] = s1 * s1;
    rb[base + 2] = s2 * s2;
}

extern "C" void kernel_launch(void* const* d_in, const int* in_sizes, int n_in,
                              void* d_out, int out_size, void* d_ws, size_t ws_size,
                              hipStream_t stream) {
    const float* out = (const float*)d_in[0];
    const float* tgt = (const float*)d_in[1];
    const int* nidx = (const int*)d_in[2];
    const float* nw = (const float*)d_in[3];
    float* res = (float*)d_out;

    const size_t need = (size_t)NN * TROW * sizeof(_Float16);  // 9.6 MB
    if (ws_size >= need) {
        _Float16* td = (_Float16*)d_ws;
        lap_pass1<<<NN / NB1, 256, 0, stream>>>(out, tgt, td);
        lap_pass2<<<NN / NB2, 320, 0, stream>>>(td, nidx, nw, res);
    } else {
        dim3 grid((NN + 255) / 256, BB);
        lap_naive<<<grid, dim3(256), 0, stream>>>(out, tgt, nidx, nw, res);
    }
}